// Round 9
// baseline (404.918 us; speedup 1.0000x reference)
//
#include <hip/hip_runtime.h>

// Problem constants (B=64, T=512, I=256, H=512)
#define BATCH 64
#define TSTEPS 512
#define IDIM 256
#define HDIM 512
#define MROWS (BATCH * TSTEPS)   // 32768
#define KZ HDIM                  // zero-row index in W2T (row 512 == 0.0f)

typedef __attribute__((address_space(1))) const void gvoid;
typedef __attribute__((address_space(3))) void lvoid;

__device__ __forceinline__ void gl2lds16(const void* g, void* l) {
    // async global->LDS, 16B per lane; LDS dest = wave-uniform base + lane*16
    __builtin_amdgcn_global_load_lds((gvoid*)g, (lvoid*)l, 16, 0, 0);
}

// ---------------------------------------------------------------------------
// K0: extract center taps: W1T[i][h] = conv1_w[h][i][1] ([k][n] layout);
//                          W2T[h][j] = conv2_w[j][h][1] ([k][n] layout)
// W2T gets a 513th all-zero row (KZ=512): pad/sentinel target for the sparse
// layer-2 kernel. Adding +0.0f is bit-neutral vs the dense chain's
// fmaf(0,w,acc) at inactive ks — validated absmax 0.0 rounds 1/2/4/5/6/7/8.
// ---------------------------------------------------------------------------
__global__ void extract_weights(const float* __restrict__ c1w,
                                const float* __restrict__ c2w,
                                float* __restrict__ W1T,
                                float* __restrict__ W2T) {
    int tid = blockIdx.x * 256 + threadIdx.x;
    if (tid < IDIM * HDIM) {
        int i = tid >> 9;          // / 512
        int h = tid & 511;
        W1T[tid] = c1w[(h * IDIM + i) * 3 + 1];
    }
    if (tid < HDIM * HDIM) {
        int h = tid >> 9;
        int j = tid & 511;
        W2T[tid] = c2w[(j * HDIM + h) * 3 + 1];
    }
    if (tid < HDIM) {
        W2T[HDIM * HDIM + tid] = 0.0f;   // zero pad row
    }
}

// ---------------------------------------------------------------------------
// K1 dense GEMM — ROUND-4 SHAPE VERBATIM (best measured; LDS-pipe floor).
// NUMERICS CONTRACT: each output is ONE sequential fmaf chain, k ascending.
// Used ONLY for layer 1 (x @ W1T, K=256): x is dense Gaussian.
// ---------------------------------------------------------------------------
#define BM 128
#define BN 128
#define BK 16

__global__ __launch_bounds__(256, 2) void gemm_f32(const float* __restrict__ A,
                                                   const float* __restrict__ BT,
                                                   const float* __restrict__ bias,
                                                   float* __restrict__ C,
                                                   int K, int addBias) {
    __shared__ __align__(16) float As[BK * BM];   // [k][m]  8 KB
    __shared__ __align__(16) float Bs[BK * BN];   // [k][n]  8 KB

    const int N = HDIM;
    int tid  = threadIdx.x;
    int lane = tid & 63;
    int wave = tid >> 6;
    int row0 = blockIdx.x * BM;
    int col0 = blockIdx.y * BN;
    int wm = (wave >> 1) * 64;
    int wn = (wave & 1) * 64;
    int mbase = wm + (lane >> 3) * 8;
    int nbase = wn + (lane & 7) * 8;

    float acc[8][8];
#pragma unroll
    for (int i = 0; i < 8; i++)
#pragma unroll
        for (int j = 0; j < 8; j++) acc[i][j] = 0.0f;

    int ar = tid >> 1;
    int ak = (tid & 1) * 8;
    const float* ap = A + (size_t)(row0 + ar) * K + ak;

    const char* bp = (const char*)(BT + (size_t)(tid >> 5) * N + col0) + (tid & 31) * 16;
    char* bld = (char*)Bs + tid * 16;
    const size_t bRow8 = (size_t)8 * N * sizeof(float);

    for (int k0 = 0; k0 < K; k0 += BK) {
        gl2lds16(bp, bld);
        gl2lds16(bp + bRow8, bld + 4096);
        float4 a0 = *(const float4*)(ap);
        float4 a1 = *(const float4*)(ap + 4);
        ap += BK;
        bp += (size_t)BK * N * sizeof(float);
        As[(ak + 0) * BM + ar] = a0.x;
        As[(ak + 1) * BM + ar] = a0.y;
        As[(ak + 2) * BM + ar] = a0.z;
        As[(ak + 3) * BM + ar] = a0.w;
        As[(ak + 4) * BM + ar] = a1.x;
        As[(ak + 5) * BM + ar] = a1.y;
        As[(ak + 6) * BM + ar] = a1.z;
        As[(ak + 7) * BM + ar] = a1.w;
        __syncthreads();

#pragma unroll
        for (int k = 0; k < BK; k++) {
            float4 av0 = *(const float4*)&As[k * BM + mbase];
            float4 av1 = *(const float4*)&As[k * BM + mbase + 4];
            float4 bv0 = *(const float4*)&Bs[k * BN + nbase];
            float4 bv1 = *(const float4*)&Bs[k * BN + nbase + 4];
            float a8[8] = {av0.x, av0.y, av0.z, av0.w, av1.x, av1.y, av1.z, av1.w};
            float b8[8] = {bv0.x, bv0.y, bv0.z, bv0.w, bv1.x, bv1.y, bv1.z, bv1.w};
#pragma unroll
            for (int i = 0; i < 8; i++)
#pragma unroll
                for (int j = 0; j < 8; j++)
                    acc[i][j] = fmaf(a8[i], b8[j], acc[i][j]);
        }
        __syncthreads();
    }

    float bb[8];
#pragma unroll
    for (int j = 0; j < 8; j++)
        bb[j] = addBias ? bias[col0 + nbase + j] : 0.0f;
#pragma unroll
    for (int i = 0; i < 8; i++) {
        int row = row0 + mbase + i;
        float4* cp = (float4*)&C[(size_t)row * N + col0 + nbase];
        cp[0] = (float4){acc[i][0] + bb[0], acc[i][1] + bb[1],
                         acc[i][2] + bb[2], acc[i][3] + bb[3]};
        cp[1] = (float4){acc[i][4] + bb[4], acc[i][5] + bb[5],
                         acc[i][6] + bb[6], acc[i][7] + bb[7]};
    }
}

// ---------------------------------------------------------------------------
// K2: per-(b,h) LIF scan, ping-pong register prefetch (arithmetic VERBATIM).
// Emits spike BITMASKS (__ballot) instead of float s1.
// ---------------------------------------------------------------------------
__global__ void lif_scan1(const float* __restrict__ z1,
                          unsigned long long* __restrict__ masks,
                          const float* __restrict__ th_p) {
    int gtid = blockIdx.x * blockDim.x + threadIdx.x;   // 0..32767
    int b = gtid >> 9;
    int h = gtid & 511;
    int lane = threadIdx.x & 63;
    int w = h >> 6;                                     // mask word index 0..7
    float th = *th_p;
    const float* zp = z1 + (size_t)b * TSTEPS * HDIM + h;
    unsigned long long* mp = masks + (size_t)b * TSTEPS * 8 + w;
    float m = 0.0f;
    float bufA[16], bufB[16];
#pragma unroll
    for (int i = 0; i < 16; i++) bufA[i] = zp[(size_t)i * HDIM];
    for (int t0 = 0; t0 < TSTEPS; t0 += 32) {
#pragma unroll
        for (int i = 0; i < 16; i++) bufB[i] = zp[(size_t)(t0 + 16 + i) * HDIM];
        {
#pragma unroll
            for (int i = 0; i < 16; i++) {
                m += bufA[i];
                float thr = m / th - 1.0f;
                unsigned long long bal = __ballot(thr >= 0.0f);
                if (lane == 0) mp[(size_t)(t0 + i) * 8] = bal;
                if (thr > 0.0f) m -= th;
            }
        }
        if (t0 + 32 < TSTEPS) {
#pragma unroll
            for (int i = 0; i < 16; i++) bufA[i] = zp[(size_t)(t0 + 32 + i) * HDIM];
        }
        {
#pragma unroll
            for (int i = 0; i < 16; i++) {
                m += bufB[i];
                float thr = m / th - 1.0f;
                unsigned long long bal = __ballot(thr >= 0.0f);
                if (lane == 0) mp[(size_t)(t0 + 16 + i) * 8] = bal;
                if (thr > 0.0f) m -= th;
            }
        }
    }
}

// ---------------------------------------------------------------------------
// K3 v9: spike-sparse s1 @ W2T — GLOBAL->REGISTER, no LDS staging.
// Ledger: v4(d1,conf)=129.6; v5(d2,0c)=148; v6(RPB2)=145; v7(d3,0c)=121.8;
// v8(d3,half-LDS,2x occupancy)=122.3 — occupancy doubling changed NOTHING,
// so not latency-bound; the 4KB/chunk LDS round-trip (write+read) on top of
// the 2KB L2 read is the removable cost (lane l consumes exactly the 32B it
// staged). v9 loads W2T rows straight into named rotating float4 buffers
// (a/b/c/d; no dynamic indexing, rule #20), depth-4: issue chunk g+3 ->
// sched_barrier(0) -> consume chunk g. No inline-asm loads (round-3 crash)
// and no manual vmcnt: the compiler emits correctly-counted vmcnt for its
// own register loads; sched_barrier(0) only pins issue order (round-2's
// re-roll). klist padded to %4 with KZ (consumed as +0.0, bit-neutral,
// validated rounds 1-8) + 4 KZ sentinels so the load stream never branches;
// klist quads prefetched one rotation early (1 ds_read_b64 per 4 chunks).
// 256-thr blocks (wave=row) lift the 1-wave-workgroup occupancy cap; LDS
// drops to 4.2KB. Per-output add order strictly k-ascending -> bit-exact.
// ---------------------------------------------------------------------------
#define SB __builtin_amdgcn_sched_barrier(0)

#define LOADQ(X0, X1, kk)                                                   \
    {                                                                       \
        const float* p_ = W2T + (size_t)(kk) * HDIM + (lane << 2);          \
        X0 = *(const float4*)(p_);                                          \
        X1 = *(const float4*)(p_ + 256);                                    \
    }

#define ACCQ(X0, X1)                                                        \
    s0.x += X0.x; s0.y += X0.y; s0.z += X0.z; s0.w += X0.w;                 \
    s1.x += X1.x; s1.y += X1.y; s1.z += X1.z; s1.w += X1.w;

__global__ __launch_bounds__(256) void spmm_spikes(
        const unsigned long long* __restrict__ masks,
        const float* __restrict__ W2T,
        float* __restrict__ C) {
    __shared__ __align__(16) unsigned short klist[4][520];   // 4.2 KB
    int lane = threadIdx.x & 63;
    int wave = threadIdx.x >> 6;
    int m = blockIdx.x * 4 + wave;                 // wave = one output row
    const unsigned long long* mrow = masks + (size_t)m * 8;
    unsigned short* klw = klist[wave];

    // Load all 8 mask words (wave-uniform address, independent).
    unsigned long long wv[8];
#pragma unroll
    for (int c = 0; c < 8; c++) wv[c] = mrow[c];

    // Wave-parallel k-list build (rounds 1-8 verified): lane l owns bit l of
    // each word; slot = count of set bits below. Pad to %4 with KZ, then 4
    // KZ sentinels (loaded by the pipeline tail, never consumed).
    int cnt = 0;
#pragma unroll
    for (int c = 0; c < 8; c++) {
        unsigned long long bal = wv[c];
        int below = (int)__popcll(bal & ((1ull << lane) - 1ull));
        if ((bal >> lane) & 1ull)
            klw[cnt + below] = (unsigned short)((c << 6) | lane);
        cnt += (int)__popcll(bal);
    }
    int pad = (-cnt) & 3;
    if (lane < pad) klw[cnt + lane] = (unsigned short)KZ;
    cnt += pad;
    cnt = __builtin_amdgcn_readfirstlane(cnt);
    if (lane < 4) klw[cnt + lane] = (unsigned short)KZ;   // sentinels

    float4 s0 = {0.0f, 0.0f, 0.0f, 0.0f};
    float4 s1 = {0.0f, 0.0f, 0.0f, 0.0f};

    if (cnt > 0) {                                 // cnt % 4 == 0, cnt >= 4
        float4 a0, a1, b0, b1, c0, c1, d0, d1;
        ushort4 qc = *(const ushort4*)(klw);       // quad for chunks 0..3
        LOADQ(a0, a1, qc.x);
        LOADQ(b0, b1, qc.y);
        LOADQ(c0, c1, qc.z);
        for (int i = 0; i < cnt; i += 4) {
            ushort4 qn = *(const ushort4*)(klw + i + 4);   // next quad (sentinel-safe)
            LOADQ(d0, d1, qc.w); SB;
            ACCQ(a0, a1); SB;
            LOADQ(a0, a1, qn.x); SB;
            ACCQ(b0, b1); SB;
            LOADQ(b0, b1, qn.y); SB;
            ACCQ(c0, c1); SB;
            LOADQ(c0, c1, qn.z); SB;
            ACCQ(d0, d1); SB;
            qc = qn;
        }
    }

    // lane l writes cols {4l..4l+3} and {256+4l..256+4l+3}: two 1KB stores.
    float* crow = C + (size_t)m * HDIM;
    *(float4*)(crow + (lane << 2))       = s0;
    *(float4*)(crow + 256 + (lane << 2)) = s1;
}

// ---------------------------------------------------------------------------
// K4: per-(b,j) scan: m2 = (m2 + raw[t]) + bias, spike/reset -> out.
// Ping-pong prefetch (verbatim).
// ---------------------------------------------------------------------------
__global__ void lif_scan2(const float* __restrict__ raw,
                          const float* __restrict__ b2,
                          const float* __restrict__ th_p,
                          float* __restrict__ out) {
    int gtid = blockIdx.x * blockDim.x + threadIdx.x;   // 0..32767
    int b = gtid >> 9;
    int j = gtid & 511;
    float th = *th_p;
    float bias = b2[j];
    const float* rp = raw + (size_t)b * TSTEPS * HDIM + j;
    float* op = out + (size_t)b * TSTEPS * HDIM + j;
    float m = 0.0f;
    float bufA[16], bufB[16];
#pragma unroll
    for (int i = 0; i < 16; i++) bufA[i] = rp[(size_t)i * HDIM];
    for (int t0 = 0; t0 < TSTEPS; t0 += 32) {
#pragma unroll
        for (int i = 0; i < 16; i++) bufB[i] = rp[(size_t)(t0 + 16 + i) * HDIM];
        {
            float ss[16];
#pragma unroll
            for (int i = 0; i < 16; i++) {
                m = (m + bufA[i]) + bias;
                float thr = m / th - 1.0f;
                ss[i] = (thr >= 0.0f) ? 1.0f : 0.0f;
                if (thr > 0.0f) m -= th;
            }
#pragma unroll
            for (int i = 0; i < 16; i++) op[(size_t)(t0 + i) * HDIM] = ss[i];
        }
        if (t0 + 32 < TSTEPS) {
#pragma unroll
            for (int i = 0; i < 16; i++) bufA[i] = rp[(size_t)(t0 + 32 + i) * HDIM];
        }
        {
            float ss[16];
#pragma unroll
            for (int i = 0; i < 16; i++) {
                m = (m + bufB[i]) + bias;
                float thr = m / th - 1.0f;
                ss[i] = (thr >= 0.0f) ? 1.0f : 0.0f;
                if (thr > 0.0f) m -= th;
            }
#pragma unroll
            for (int i = 0; i < 16; i++) op[(size_t)(t0 + 16 + i) * HDIM] = ss[i];
        }
    }
}

// ---------------------------------------------------------------------------
extern "C" void kernel_launch(void* const* d_in, const int* in_sizes, int n_in,
                              void* d_out, int out_size, void* d_ws, size_t ws_size,
                              hipStream_t stream) {
    const float* x    = (const float*)d_in[0];   // (64, 512, 256)
    const float* c1w  = (const float*)d_in[1];   // (512, 256, 3)
    const float* c1b  = (const float*)d_in[2];   // (512,)
    const float* c2w  = (const float*)d_in[3];   // (512, 512, 3)
    const float* c2b  = (const float*)d_in[4];   // (512,)
    const float* th1  = (const float*)d_in[5];   // scalar
    const float* th2  = (const float*)d_in[6];   // scalar
    float* out = (float*)d_out;                  // (64, 512, 512)

    // Workspace layout (floats):
    //   W1T  : 131072     (512 KB)  [k=i][n=h]
    //   W2T  : 513*512    (~1 MB)   [k=h][n=j] + zero pad row at k=512
    //   bufA : 16777216   (64 MB)   z1, later z2raw  [m][n]
    //   masks: 32768*8 u64 (2 MB)   spike bitmasks   [m][kword]
    float* W1T  = (float*)d_ws;
    float* W2T  = W1T + IDIM * HDIM;
    float* bufA = W2T + (HDIM + 1) * HDIM;
    unsigned long long* masks = (unsigned long long*)(bufA + (size_t)MROWS * HDIM);

    // K0: weight extraction (+ zero pad row)
    extract_weights<<<(HDIM * HDIM + 255) / 256, 256, 0, stream>>>(c1w, c2w, W1T, W2T);

    // K1: z1 = x @ W1T + b1   (M=32768, K=256, N=512) -> bufA
    {
        dim3 grid(MROWS / BM, HDIM / BN);
        gemm_f32<<<grid, 256, 0, stream>>>(x, W1T, c1b, bufA, IDIM, 1);
    }

    // K2: s1 scan -> spike bitmasks (no float s1 materialization)
    lif_scan1<<<MROWS / 64, 64, 0, stream>>>(bufA, masks, th1);

    // K3: z2raw[m][:] = sum_{k in spikes(m)} W2T[k][:]  (bit-exact sparse)
    spmm_spikes<<<MROWS / 4, 256, 0, stream>>>(masks, W2T, bufA);

    // K4: s2 scan -> out
    lif_scan2<<<MROWS / 64, 64, 0, stream>>>(bufA, c2b, th2, out);
}

// Round 10
// 368.412 us; speedup vs baseline: 1.0991x; 1.0991x over previous
//
#include <hip/hip_runtime.h>

// Problem constants (B=64, T=512, I=256, H=512)
#define BATCH 64
#define TSTEPS 512
#define IDIM 256
#define HDIM 512
#define MROWS (BATCH * TSTEPS)   // 32768
#define KZ HDIM                  // zero-row index in W2T (row 512 == 0.0f)

typedef __attribute__((address_space(1))) const void gvoid;
typedef __attribute__((address_space(3))) void lvoid;

__device__ __forceinline__ void gl2lds16(const void* g, void* l) {
    // async global->LDS, 16B per lane; LDS dest = wave-uniform base + lane*16
    __builtin_amdgcn_global_load_lds((gvoid*)g, (lvoid*)l, 16, 0, 0);
}

// ---------------------------------------------------------------------------
// K0: extract center taps: W1T[i][h] = conv1_w[h][i][1] ([k][n] layout);
//                          W2T[h][j] = conv2_w[j][h][1] ([k][n] layout)
// W2T keeps a 513th all-zero row (KZ) — pad target for the sparse layer-2
// kernel; +0.0f adds are bit-neutral (validated absmax 0.0 rounds 1-9).
// ---------------------------------------------------------------------------
__global__ void extract_weights(const float* __restrict__ c1w,
                                const float* __restrict__ c2w,
                                float* __restrict__ W1T,
                                float* __restrict__ W2T) {
    int tid = blockIdx.x * 256 + threadIdx.x;
    if (tid < IDIM * HDIM) {
        int i = tid >> 9;          // / 512
        int h = tid & 511;
        W1T[tid] = c1w[(h * IDIM + i) * 3 + 1];
    }
    if (tid < HDIM * HDIM) {
        int h = tid >> 9;
        int j = tid & 511;
        W2T[tid] = c2w[(j * HDIM + h) * 3 + 1];
    }
    if (tid < HDIM) {
        W2T[HDIM * HDIM + tid] = 0.0f;   // zero pad row
    }
}

// ---------------------------------------------------------------------------
// K1 dense GEMM — ROUND-4 SHAPE VERBATIM (best measured; LDS-pipe floor).
// NUMERICS CONTRACT: each output is ONE sequential fmaf chain, k ascending.
// Used ONLY for layer 1 (x @ W1T, K=256): x is dense Gaussian.
// ---------------------------------------------------------------------------
#define BM 128
#define BN 128
#define BK 16

__global__ __launch_bounds__(256, 2) void gemm_f32(const float* __restrict__ A,
                                                   const float* __restrict__ BT,
                                                   const float* __restrict__ bias,
                                                   float* __restrict__ C,
                                                   int K, int addBias) {
    __shared__ __align__(16) float As[BK * BM];   // [k][m]  8 KB
    __shared__ __align__(16) float Bs[BK * BN];   // [k][n]  8 KB

    const int N = HDIM;
    int tid  = threadIdx.x;
    int lane = tid & 63;
    int wave = tid >> 6;
    int row0 = blockIdx.x * BM;
    int col0 = blockIdx.y * BN;
    int wm = (wave >> 1) * 64;
    int wn = (wave & 1) * 64;
    int mbase = wm + (lane >> 3) * 8;
    int nbase = wn + (lane & 7) * 8;

    float acc[8][8];
#pragma unroll
    for (int i = 0; i < 8; i++)
#pragma unroll
        for (int j = 0; j < 8; j++) acc[i][j] = 0.0f;

    int ar = tid >> 1;
    int ak = (tid & 1) * 8;
    const float* ap = A + (size_t)(row0 + ar) * K + ak;

    const char* bp = (const char*)(BT + (size_t)(tid >> 5) * N + col0) + (tid & 31) * 16;
    char* bld = (char*)Bs + tid * 16;
    const size_t bRow8 = (size_t)8 * N * sizeof(float);

    for (int k0 = 0; k0 < K; k0 += BK) {
        gl2lds16(bp, bld);
        gl2lds16(bp + bRow8, bld + 4096);
        float4 a0 = *(const float4*)(ap);
        float4 a1 = *(const float4*)(ap + 4);
        ap += BK;
        bp += (size_t)BK * N * sizeof(float);
        As[(ak + 0) * BM + ar] = a0.x;
        As[(ak + 1) * BM + ar] = a0.y;
        As[(ak + 2) * BM + ar] = a0.z;
        As[(ak + 3) * BM + ar] = a0.w;
        As[(ak + 4) * BM + ar] = a1.x;
        As[(ak + 5) * BM + ar] = a1.y;
        As[(ak + 6) * BM + ar] = a1.z;
        As[(ak + 7) * BM + ar] = a1.w;
        __syncthreads();

#pragma unroll
        for (int k = 0; k < BK; k++) {
            float4 av0 = *(const float4*)&As[k * BM + mbase];
            float4 av1 = *(const float4*)&As[k * BM + mbase + 4];
            float4 bv0 = *(const float4*)&Bs[k * BN + nbase];
            float4 bv1 = *(const float4*)&Bs[k * BN + nbase + 4];
            float a8[8] = {av0.x, av0.y, av0.z, av0.w, av1.x, av1.y, av1.z, av1.w};
            float b8[8] = {bv0.x, bv0.y, bv0.z, bv0.w, bv1.x, bv1.y, bv1.z, bv1.w};
#pragma unroll
            for (int i = 0; i < 8; i++)
#pragma unroll
                for (int j = 0; j < 8; j++)
                    acc[i][j] = fmaf(a8[i], b8[j], acc[i][j]);
        }
        __syncthreads();
    }

    float bb[8];
#pragma unroll
    for (int j = 0; j < 8; j++)
        bb[j] = addBias ? bias[col0 + nbase + j] : 0.0f;
#pragma unroll
    for (int i = 0; i < 8; i++) {
        int row = row0 + mbase + i;
        float4* cp = (float4*)&C[(size_t)row * N + col0 + nbase];
        cp[0] = (float4){acc[i][0] + bb[0], acc[i][1] + bb[1],
                         acc[i][2] + bb[2], acc[i][3] + bb[3]};
        cp[1] = (float4){acc[i][4] + bb[4], acc[i][5] + bb[5],
                         acc[i][6] + bb[6], acc[i][7] + bb[7]};
    }
}

// ---------------------------------------------------------------------------
// K2 v2: per-(b,h) LIF scan, DEPTH-32 ping-pong (was 16). The scans have a
// hard 512-wave cap (2 waves/CU) — latency hiding is pure ILP. Depth-16 kept
// only 8 KB/CU in flight vs the ~22 KB latency-BW product (36% of HBM rate);
// depth-32 doubles that. VGPR ~90 is free at 2 waves/CU. Per-element
// arithmetic chain VERBATIM (m += z; thr = m/th-1; spike = thr>=0; reset if
// thr>0). Emits spike BITMASKS (__ballot).
// ---------------------------------------------------------------------------
__global__ __launch_bounds__(64, 1) void lif_scan1(
        const float* __restrict__ z1,
        unsigned long long* __restrict__ masks,
        const float* __restrict__ th_p) {
    int gtid = blockIdx.x * blockDim.x + threadIdx.x;   // 0..32767
    int b = gtid >> 9;
    int h = gtid & 511;
    int lane = threadIdx.x & 63;
    int w = h >> 6;                                     // mask word index 0..7
    float th = *th_p;
    const float* zp = z1 + (size_t)b * TSTEPS * HDIM + h;
    unsigned long long* mp = masks + (size_t)b * TSTEPS * 8 + w;
    float m = 0.0f;
    float bufA[32], bufB[32];
#pragma unroll
    for (int i = 0; i < 32; i++) bufA[i] = zp[(size_t)i * HDIM];
    for (int t0 = 0; t0 < TSTEPS; t0 += 64) {
#pragma unroll
        for (int i = 0; i < 32; i++) bufB[i] = zp[(size_t)(t0 + 32 + i) * HDIM];
        {
#pragma unroll
            for (int i = 0; i < 32; i++) {
                m += bufA[i];
                float thr = m / th - 1.0f;
                unsigned long long bal = __ballot(thr >= 0.0f);
                if (lane == 0) mp[(size_t)(t0 + i) * 8] = bal;
                if (thr > 0.0f) m -= th;
            }
        }
        if (t0 + 64 < TSTEPS) {
#pragma unroll
            for (int i = 0; i < 32; i++) bufA[i] = zp[(size_t)(t0 + 64 + i) * HDIM];
        }
        {
#pragma unroll
            for (int i = 0; i < 32; i++) {
                m += bufB[i];
                float thr = m / th - 1.0f;
                unsigned long long bal = __ballot(thr >= 0.0f);
                if (lane == 0) mp[(size_t)(t0 + 32 + i) * 8] = bal;
                if (thr > 0.0f) m -= th;
            }
        }
    }
}

// ---------------------------------------------------------------------------
// K3 v8 (RESTORED — best measured, 122 µs): spike-sparse s1 @ W2T via gl2lds
// depth-3 pipeline, CH=1, conflict-free consume. Ledger: v4=129.6; v5=148;
// v6=145; v7=121.8; v8=122.3; v9(reg)=145 (compiler re-rolled, VGPR=32 —
// third failure of reg-pipelines; do not retry). v7≈v8 at 2x occupancy =>
// shared per-CU L1+LDS path ceiling => K3 at structural floor for this
// design. Per-output add order strictly k-ascending -> bit-exact.
// ---------------------------------------------------------------------------
#define NBUF 4

__global__ __launch_bounds__(64, 1) void spmm_spikes(
        const unsigned long long* __restrict__ masks,
        const float* __restrict__ W2T,
        float* __restrict__ C) {
    __shared__ __align__(16) float stage[NBUF][HDIM];      // 8 KB
    __shared__ __align__(16) unsigned short klist[512];    // 1 KB
    int lane = threadIdx.x;                                // 1 wave/block
    int m = blockIdx.x;                                    // output row
    const unsigned long long* mrow = masks + (size_t)m * 8;

    // Load all 8 mask words (wave-uniform address -> scalar loads).
    unsigned long long wv[8];
#pragma unroll
    for (int c = 0; c < 8; c++) wv[c] = mrow[c];

    // Wave-parallel k-list build (rounds 1-8 verified): lane l owns bit l of
    // each word; slot = count of set bits below. No padding (CH=1).
    int cnt = 0;
#pragma unroll
    for (int c = 0; c < 8; c++) {
        unsigned long long bal = wv[c];
        int below = (int)__popcll(bal & ((1ull << lane) - 1ull));
        if ((bal >> lane) & 1ull)
            klist[cnt + below] = (unsigned short)((c << 6) | lane);
        cnt += (int)__popcll(bal);
    }
    int nch = __builtin_amdgcn_readfirstlane(cnt);         // chunks of 1 row

    float4 s0 = {0.0f, 0.0f, 0.0f, 0.0f};
    float4 s1 = {0.0f, 0.0f, 0.0f, 0.0f};

    // Stage chunk g (1 W2T row = 2KB) into stage[buf]: 2 x gl2lds16, each
    // 1KB (64 lanes x 16B, linear; rounds 4-8 verified convention).
#define STAGE(buf, g)                                                       \
    {                                                                       \
        unsigned short k_ = klist[g];                                       \
        const float* g0_ = W2T + (size_t)k_ * HDIM + (lane << 2);           \
        float* l_ = &stage[buf][0] + (lane << 2);                           \
        gl2lds16(g0_,       l_);                                            \
        gl2lds16(g0_ + 256, l_ + 256);                                      \
    }

    if (nch > 0) {
        // Drain prologue VMEM so vmcnt counts staging loads only.
        asm volatile("s_waitcnt vmcnt(0)" ::: "memory");
        __builtin_amdgcn_sched_barrier(0);
        STAGE(0, 0);
        if (nch > 1) STAGE(1, 1);
        if (nch > 2) STAGE(2, 2);
        if (nch > 3) STAGE(3, 3);
        for (int g = 0; g < nch; g++) {
            __builtin_amdgcn_sched_barrier(0);
            int rem = nch - 1 - g;                  // chunks still in flight
            if (rem >= 3) {
                asm volatile("s_waitcnt vmcnt(6)" ::: "memory");
            } else if (rem == 2) {
                asm volatile("s_waitcnt vmcnt(4)" ::: "memory");
            } else if (rem == 1) {
                asm volatile("s_waitcnt vmcnt(2)" ::: "memory");
            } else {
                asm volatile("s_waitcnt vmcnt(0)" ::: "memory");
            }
            __builtin_amdgcn_sched_barrier(0);      // rule #18: pin reads below
            const float* base = &stage[g & (NBUF - 1)][0] + (lane << 2);
            float4 w0 = *(const float4*)(base);            // cols 4l..4l+3
            float4 w1 = *(const float4*)(base + 256);      // cols 256+4l..
            s0.x += w0.x; s0.y += w0.y; s0.z += w0.z; s0.w += w0.w;
            s1.x += w1.x; s1.y += w1.y; s1.z += w1.z; s1.w += w1.w;
            __builtin_amdgcn_sched_barrier(0);      // keep consume in its phase
            if (g + NBUF < nch) STAGE(g & (NBUF - 1), g + NBUF);
        }
    }
#undef STAGE

    // lane l writes cols {4l..4l+3} and {256+4l..256+4l+3}: two 1KB stores.
    float* crow = C + (size_t)m * HDIM;
    *(float4*)(crow + (lane << 2))       = s0;
    *(float4*)(crow + 256 + (lane << 2)) = s1;
}

// ---------------------------------------------------------------------------
// K4 v2: per-(b,j) scan, DEPTH-32 ping-pong (was 16; same rationale as K2).
// Arithmetic chain VERBATIM: m2 = (m2 + raw[t]) + bias, spike/reset -> out.
// ---------------------------------------------------------------------------
__global__ __launch_bounds__(64, 1) void lif_scan2(
        const float* __restrict__ raw,
        const float* __restrict__ b2,
        const float* __restrict__ th_p,
        float* __restrict__ out) {
    int gtid = blockIdx.x * blockDim.x + threadIdx.x;   // 0..32767
    int b = gtid >> 9;
    int j = gtid & 511;
    float th = *th_p;
    float bias = b2[j];
    const float* rp = raw + (size_t)b * TSTEPS * HDIM + j;
    float* op = out + (size_t)b * TSTEPS * HDIM + j;
    float m = 0.0f;
    float bufA[32], bufB[32];
#pragma unroll
    for (int i = 0; i < 32; i++) bufA[i] = rp[(size_t)i * HDIM];
    for (int t0 = 0; t0 < TSTEPS; t0 += 64) {
#pragma unroll
        for (int i = 0; i < 32; i++) bufB[i] = rp[(size_t)(t0 + 32 + i) * HDIM];
        {
            float ss[32];
#pragma unroll
            for (int i = 0; i < 32; i++) {
                m = (m + bufA[i]) + bias;
                float thr = m / th - 1.0f;
                ss[i] = (thr >= 0.0f) ? 1.0f : 0.0f;
                if (thr > 0.0f) m -= th;
            }
#pragma unroll
            for (int i = 0; i < 32; i++) op[(size_t)(t0 + i) * HDIM] = ss[i];
        }
        if (t0 + 64 < TSTEPS) {
#pragma unroll
            for (int i = 0; i < 32; i++) bufA[i] = rp[(size_t)(t0 + 64 + i) * HDIM];
        }
        {
            float ss[32];
#pragma unroll
            for (int i = 0; i < 32; i++) {
                m = (m + bufB[i]) + bias;
                float thr = m / th - 1.0f;
                ss[i] = (thr >= 0.0f) ? 1.0f : 0.0f;
                if (thr > 0.0f) m -= th;
            }
#pragma unroll
            for (int i = 0; i < 32; i++) op[(size_t)(t0 + 32 + i) * HDIM] = ss[i];
        }
    }
}

// ---------------------------------------------------------------------------
extern "C" void kernel_launch(void* const* d_in, const int* in_sizes, int n_in,
                              void* d_out, int out_size, void* d_ws, size_t ws_size,
                              hipStream_t stream) {
    const float* x    = (const float*)d_in[0];   // (64, 512, 256)
    const float* c1w  = (const float*)d_in[1];   // (512, 256, 3)
    const float* c1b  = (const float*)d_in[2];   // (512,)
    const float* c2w  = (const float*)d_in[3];   // (512, 512, 3)
    const float* c2b  = (const float*)d_in[4];   // (512,)
    const float* th1  = (const float*)d_in[5];   // scalar
    const float* th2  = (const float*)d_in[6];   // scalar
    float* out = (float*)d_out;                  // (64, 512, 512)

    // Workspace layout (floats):
    //   W1T  : 131072     (512 KB)  [k=i][n=h]
    //   W2T  : 513*512    (~1 MB)   [k=h][n=j] + zero pad row at k=512
    //   bufA : 16777216   (64 MB)   z1, later z2raw  [m][n]
    //   masks: 32768*8 u64 (2 MB)   spike bitmasks   [m][kword]
    float* W1T  = (float*)d_ws;
    float* W2T  = W1T + IDIM * HDIM;
    float* bufA = W2T + (HDIM + 1) * HDIM;
    unsigned long long* masks = (unsigned long long*)(bufA + (size_t)MROWS * HDIM);

    // K0: weight extraction (+ zero pad row)
    extract_weights<<<(HDIM * HDIM + 255) / 256, 256, 0, stream>>>(c1w, c2w, W1T, W2T);

    // K1: z1 = x @ W1T + b1   (M=32768, K=256, N=512) -> bufA
    {
        dim3 grid(MROWS / BM, HDIM / BN);
        gemm_f32<<<grid, 256, 0, stream>>>(x, W1T, c1b, bufA, IDIM, 1);
    }

    // K2: s1 scan -> spike bitmasks (no float s1 materialization)
    lif_scan1<<<MROWS / 64, 64, 0, stream>>>(bufA, masks, th1);

    // K3: z2raw[m][:] = sum_{k in spikes(m)} W2T[k][:]  (bit-exact sparse)
    spmm_spikes<<<MROWS, 64, 0, stream>>>(masks, W2T, bufA);

    // K4: s2 scan -> out
    lif_scan2<<<MROWS / 64, 64, 0, stream>>>(bufA, c2b, th2, out);
}

// Round 12
// 349.348 us; speedup vs baseline: 1.1591x; 1.0546x over previous
//
#include <hip/hip_runtime.h>

// Problem constants (B=64, T=512, I=256, H=512)
#define BATCH 64
#define TSTEPS 512
#define IDIM 256
#define HDIM 512
#define MROWS (BATCH * TSTEPS)   // 32768
#define KZ HDIM                  // zero-row index in W2T (row 512 == 0.0f)

typedef __attribute__((address_space(1))) const void gvoid;
typedef __attribute__((address_space(3))) void lvoid;

__device__ __forceinline__ void gl2lds16(const void* g, void* l) {
    // async global->LDS, 16B per lane; LDS dest = wave-uniform base + lane*16
    __builtin_amdgcn_global_load_lds((gvoid*)g, (lvoid*)l, 16, 0, 0);
}

// ---------------------------------------------------------------------------
// K0: extract center taps: W1T[i][h] = conv1_w[h][i][1] ([k][n] layout);
//                          W2T[h][j] = conv2_w[j][h][1] ([k][n] layout)
// W2T keeps a 513th all-zero row (KZ) — pad target for the sparse layer-2
// kernel; +0.0f adds are bit-neutral (validated absmax 0.0 rounds 1-10).
// ---------------------------------------------------------------------------
__global__ void extract_weights(const float* __restrict__ c1w,
                                const float* __restrict__ c2w,
                                float* __restrict__ W1T,
                                float* __restrict__ W2T) {
    int tid = blockIdx.x * 256 + threadIdx.x;
    if (tid < IDIM * HDIM) {
        int i = tid >> 9;          // / 512
        int h = tid & 511;
        W1T[tid] = c1w[(h * IDIM + i) * 3 + 1];
    }
    if (tid < HDIM * HDIM) {
        int h = tid >> 9;
        int j = tid & 511;
        W2T[tid] = c2w[(j * HDIM + h) * 3 + 1];
    }
    if (tid < HDIM) {
        W2T[HDIM * HDIM + tid] = 0.0f;   // zero pad row
    }
}

// ---------------------------------------------------------------------------
// K1 dense GEMM — ROUND-4 SHAPE VERBATIM (best measured; LDS-pipe floor).
// NUMERICS CONTRACT: each output is ONE sequential fmaf chain, k ascending.
// Used ONLY for layer 1 (x @ W1T, K=256): x is dense Gaussian.
// ---------------------------------------------------------------------------
#define BM 128
#define BN 128
#define BK 16

__global__ __launch_bounds__(256, 2) void gemm_f32(const float* __restrict__ A,
                                                   const float* __restrict__ BT,
                                                   const float* __restrict__ bias,
                                                   float* __restrict__ C,
                                                   int K, int addBias) {
    __shared__ __align__(16) float As[BK * BM];   // [k][m]  8 KB
    __shared__ __align__(16) float Bs[BK * BN];   // [k][n]  8 KB

    const int N = HDIM;
    int tid  = threadIdx.x;
    int lane = tid & 63;
    int wave = tid >> 6;
    int row0 = blockIdx.x * BM;
    int col0 = blockIdx.y * BN;
    int wm = (wave >> 1) * 64;
    int wn = (wave & 1) * 64;
    int mbase = wm + (lane >> 3) * 8;
    int nbase = wn + (lane & 7) * 8;

    float acc[8][8];
#pragma unroll
    for (int i = 0; i < 8; i++)
#pragma unroll
        for (int j = 0; j < 8; j++) acc[i][j] = 0.0f;

    int ar = tid >> 1;
    int ak = (tid & 1) * 8;
    const float* ap = A + (size_t)(row0 + ar) * K + ak;

    const char* bp = (const char*)(BT + (size_t)(tid >> 5) * N + col0) + (tid & 31) * 16;
    char* bld = (char*)Bs + tid * 16;
    const size_t bRow8 = (size_t)8 * N * sizeof(float);

    for (int k0 = 0; k0 < K; k0 += BK) {
        gl2lds16(bp, bld);
        gl2lds16(bp + bRow8, bld + 4096);
        float4 a0 = *(const float4*)(ap);
        float4 a1 = *(const float4*)(ap + 4);
        ap += BK;
        bp += (size_t)BK * N * sizeof(float);
        As[(ak + 0) * BM + ar] = a0.x;
        As[(ak + 1) * BM + ar] = a0.y;
        As[(ak + 2) * BM + ar] = a0.z;
        As[(ak + 3) * BM + ar] = a0.w;
        As[(ak + 4) * BM + ar] = a1.x;
        As[(ak + 5) * BM + ar] = a1.y;
        As[(ak + 6) * BM + ar] = a1.z;
        As[(ak + 7) * BM + ar] = a1.w;
        __syncthreads();

#pragma unroll
        for (int k = 0; k < BK; k++) {
            float4 av0 = *(const float4*)&As[k * BM + mbase];
            float4 av1 = *(const float4*)&As[k * BM + mbase + 4];
            float4 bv0 = *(const float4*)&Bs[k * BN + nbase];
            float4 bv1 = *(const float4*)&Bs[k * BN + nbase + 4];
            float a8[8] = {av0.x, av0.y, av0.z, av0.w, av1.x, av1.y, av1.z, av1.w};
            float b8[8] = {bv0.x, bv0.y, bv0.z, bv0.w, bv1.x, bv1.y, bv1.z, bv1.w};
#pragma unroll
            for (int i = 0; i < 8; i++)
#pragma unroll
                for (int j = 0; j < 8; j++)
                    acc[i][j] = fmaf(a8[i], b8[j], acc[i][j]);
        }
        __syncthreads();
    }

    float bb[8];
#pragma unroll
    for (int j = 0; j < 8; j++)
        bb[j] = addBias ? bias[col0 + nbase + j] : 0.0f;
#pragma unroll
    for (int i = 0; i < 8; i++) {
        int row = row0 + mbase + i;
        float4* cp = (float4*)&C[(size_t)row * N + col0 + nbase];
        cp[0] = (float4){acc[i][0] + bb[0], acc[i][1] + bb[1],
                         acc[i][2] + bb[2], acc[i][3] + bb[3]};
        cp[1] = (float4){acc[i][4] + bb[4], acc[i][5] + bb[5],
                         acc[i][6] + bb[6], acc[i][7] + bb[7]};
    }
}

// ---------------------------------------------------------------------------
// K2 v3: per-(b,h) LIF scan, depth-32 ping-pong (round-10) + TH==1 FAST PATH.
// Round-10 post-mortem: depth-32 covered HBM latency; the residual is the
// serial per-step chain dominated by IEEE fp32 division (v_div_scale/rcp/
// fmas/fixup ~25-30 dependent cyc) with only 2 waves/CU (no TLP). th is 1.0
// at runtime (jnp.ones); IEEE x/1.0 == x bitwise, so thr = m - 1.0f and
// m -= 1.0f are BIT-IDENTICAL to the general path when th==1.0. Runtime
// wave-uniform branch; general divide path kept VERBATIM as fallback.
// Emits spike BITMASKS (__ballot).
// ---------------------------------------------------------------------------
__global__ __launch_bounds__(64, 1) void lif_scan1(
        const float* __restrict__ z1,
        unsigned long long* __restrict__ masks,
        const float* __restrict__ th_p) {
    int gtid = blockIdx.x * blockDim.x + threadIdx.x;   // 0..32767
    int b = gtid >> 9;
    int h = gtid & 511;
    int lane = threadIdx.x & 63;
    int w = h >> 6;                                     // mask word index 0..7
    float th = *th_p;
    const float* zp = z1 + (size_t)b * TSTEPS * HDIM + h;
    unsigned long long* mp = masks + (size_t)b * TSTEPS * 8 + w;
    float m = 0.0f;
    float bufA[32], bufB[32];
#pragma unroll
    for (int i = 0; i < 32; i++) bufA[i] = zp[(size_t)i * HDIM];
    if (th == 1.0f) {
        // FAST PATH (bit-exact for th==1.0: x/1.0 == x in IEEE RN).
        for (int t0 = 0; t0 < TSTEPS; t0 += 64) {
#pragma unroll
            for (int i = 0; i < 32; i++) bufB[i] = zp[(size_t)(t0 + 32 + i) * HDIM];
#pragma unroll
            for (int i = 0; i < 32; i++) {
                m += bufA[i];
                float thr = m - 1.0f;
                unsigned long long bal = __ballot(thr >= 0.0f);
                if (lane == 0) mp[(size_t)(t0 + i) * 8] = bal;
                if (thr > 0.0f) m -= 1.0f;
            }
            if (t0 + 64 < TSTEPS) {
#pragma unroll
                for (int i = 0; i < 32; i++) bufA[i] = zp[(size_t)(t0 + 64 + i) * HDIM];
            }
#pragma unroll
            for (int i = 0; i < 32; i++) {
                m += bufB[i];
                float thr = m - 1.0f;
                unsigned long long bal = __ballot(thr >= 0.0f);
                if (lane == 0) mp[(size_t)(t0 + 32 + i) * 8] = bal;
                if (thr > 0.0f) m -= 1.0f;
            }
        }
    } else {
        // GENERAL PATH — arithmetic chain VERBATIM (rounds 1-10).
        for (int t0 = 0; t0 < TSTEPS; t0 += 64) {
#pragma unroll
            for (int i = 0; i < 32; i++) bufB[i] = zp[(size_t)(t0 + 32 + i) * HDIM];
#pragma unroll
            for (int i = 0; i < 32; i++) {
                m += bufA[i];
                float thr = m / th - 1.0f;
                unsigned long long bal = __ballot(thr >= 0.0f);
                if (lane == 0) mp[(size_t)(t0 + i) * 8] = bal;
                if (thr > 0.0f) m -= th;
            }
            if (t0 + 64 < TSTEPS) {
#pragma unroll
                for (int i = 0; i < 32; i++) bufA[i] = zp[(size_t)(t0 + 64 + i) * HDIM];
            }
#pragma unroll
            for (int i = 0; i < 32; i++) {
                m += bufB[i];
                float thr = m / th - 1.0f;
                unsigned long long bal = __ballot(thr >= 0.0f);
                if (lane == 0) mp[(size_t)(t0 + 32 + i) * 8] = bal;
                if (thr > 0.0f) m -= th;
            }
        }
    }
}

// ---------------------------------------------------------------------------
// K3 v8 (best measured, ~122 µs — structural floor per rounds 7-9 ledger):
// spike-sparse s1 @ W2T via gl2lds depth-3 pipeline, CH=1, conflict-free
// consume. v9 reg-pipeline failed 3x (compiler re-roll); do not retry.
// Per-output add order strictly k-ascending -> bit-exact.
// ---------------------------------------------------------------------------
#define NBUF 4

__global__ __launch_bounds__(64, 1) void spmm_spikes(
        const unsigned long long* __restrict__ masks,
        const float* __restrict__ W2T,
        float* __restrict__ C) {
    __shared__ __align__(16) float stage[NBUF][HDIM];      // 8 KB
    __shared__ __align__(16) unsigned short klist[512];    // 1 KB
    int lane = threadIdx.x;                                // 1 wave/block
    int m = blockIdx.x;                                    // output row
    const unsigned long long* mrow = masks + (size_t)m * 8;

    // Load all 8 mask words (wave-uniform address -> scalar loads).
    unsigned long long wv[8];
#pragma unroll
    for (int c = 0; c < 8; c++) wv[c] = mrow[c];

    // Wave-parallel k-list build (rounds 1-10 verified): lane l owns bit l of
    // each word; slot = count of set bits below. No padding (CH=1).
    int cnt = 0;
#pragma unroll
    for (int c = 0; c < 8; c++) {
        unsigned long long bal = wv[c];
        int below = (int)__popcll(bal & ((1ull << lane) - 1ull));
        if ((bal >> lane) & 1ull)
            klist[cnt + below] = (unsigned short)((c << 6) | lane);
        cnt += (int)__popcll(bal);
    }
    int nch = __builtin_amdgcn_readfirstlane(cnt);         // chunks of 1 row

    float4 s0 = {0.0f, 0.0f, 0.0f, 0.0f};
    float4 s1 = {0.0f, 0.0f, 0.0f, 0.0f};

    // Stage chunk g (1 W2T row = 2KB) into stage[buf]: 2 x gl2lds16, each
    // 1KB (64 lanes x 16B, linear; rounds 4-10 verified convention).
#define STAGE(buf, g)                                                       \
    {                                                                       \
        unsigned short k_ = klist[g];                                       \
        const float* g0_ = W2T + (size_t)k_ * HDIM + (lane << 2);           \
        float* l_ = &stage[buf][0] + (lane << 2);                           \
        gl2lds16(g0_,       l_);                                            \
        gl2lds16(g0_ + 256, l_ + 256);                                      \
    }

    if (nch > 0) {
        // Drain prologue VMEM so vmcnt counts staging loads only.
        asm volatile("s_waitcnt vmcnt(0)" ::: "memory");
        __builtin_amdgcn_sched_barrier(0);
        STAGE(0, 0);
        if (nch > 1) STAGE(1, 1);
        if (nch > 2) STAGE(2, 2);
        if (nch > 3) STAGE(3, 3);
        for (int g = 0; g < nch; g++) {
            __builtin_amdgcn_sched_barrier(0);
            int rem = nch - 1 - g;                  // chunks still in flight
            if (rem >= 3) {
                asm volatile("s_waitcnt vmcnt(6)" ::: "memory");
            } else if (rem == 2) {
                asm volatile("s_waitcnt vmcnt(4)" ::: "memory");
            } else if (rem == 1) {
                asm volatile("s_waitcnt vmcnt(2)" ::: "memory");
            } else {
                asm volatile("s_waitcnt vmcnt(0)" ::: "memory");
            }
            __builtin_amdgcn_sched_barrier(0);      // rule #18: pin reads below
            const float* base = &stage[g & (NBUF - 1)][0] + (lane << 2);
            float4 w0 = *(const float4*)(base);            // cols 4l..4l+3
            float4 w1 = *(const float4*)(base + 256);      // cols 256+4l..
            s0.x += w0.x; s0.y += w0.y; s0.z += w0.z; s0.w += w0.w;
            s1.x += w1.x; s1.y += w1.y; s1.z += w1.z; s1.w += w1.w;
            __builtin_amdgcn_sched_barrier(0);      // keep consume in its phase
            if (g + NBUF < nch) STAGE(g & (NBUF - 1), g + NBUF);
        }
    }
#undef STAGE

    // lane l writes cols {4l..4l+3} and {256+4l..256+4l+3}: two 1KB stores.
    float* crow = C + (size_t)m * HDIM;
    *(float4*)(crow + (lane << 2))       = s0;
    *(float4*)(crow + 256 + (lane << 2)) = s1;
}

// ---------------------------------------------------------------------------
// K4 v3: per-(b,j) scan, depth-32 ping-pong + TH==1 FAST PATH (same
// rationale and bit-exactness argument as K2 v3). General path VERBATIM.
// ---------------------------------------------------------------------------
__global__ __launch_bounds__(64, 1) void lif_scan2(
        const float* __restrict__ raw,
        const float* __restrict__ b2,
        const float* __restrict__ th_p,
        float* __restrict__ out) {
    int gtid = blockIdx.x * blockDim.x + threadIdx.x;   // 0..32767
    int b = gtid >> 9;
    int j = gtid & 511;
    float th = *th_p;
    float bias = b2[j];
    const float* rp = raw + (size_t)b * TSTEPS * HDIM + j;
    float* op = out + (size_t)b * TSTEPS * HDIM + j;
    float m = 0.0f;
    float bufA[32], bufB[32];
#pragma unroll
    for (int i = 0; i < 32; i++) bufA[i] = rp[(size_t)i * HDIM];
    if (th == 1.0f) {
        // FAST PATH (bit-exact for th==1.0: x/1.0 == x in IEEE RN).
        for (int t0 = 0; t0 < TSTEPS; t0 += 64) {
#pragma unroll
            for (int i = 0; i < 32; i++) bufB[i] = rp[(size_t)(t0 + 32 + i) * HDIM];
            {
                float ss[32];
#pragma unroll
                for (int i = 0; i < 32; i++) {
                    m = (m + bufA[i]) + bias;
                    float thr = m - 1.0f;
                    ss[i] = (thr >= 0.0f) ? 1.0f : 0.0f;
                    if (thr > 0.0f) m -= 1.0f;
                }
#pragma unroll
                for (int i = 0; i < 32; i++) op[(size_t)(t0 + i) * HDIM] = ss[i];
            }
            if (t0 + 64 < TSTEPS) {
#pragma unroll
                for (int i = 0; i < 32; i++) bufA[i] = rp[(size_t)(t0 + 64 + i) * HDIM];
            }
            {
                float ss[32];
#pragma unroll
                for (int i = 0; i < 32; i++) {
                    m = (m + bufB[i]) + bias;
                    float thr = m - 1.0f;
                    ss[i] = (thr >= 0.0f) ? 1.0f : 0.0f;
                    if (thr > 0.0f) m -= 1.0f;
                }
#pragma unroll
                for (int i = 0; i < 32; i++) op[(size_t)(t0 + 32 + i) * HDIM] = ss[i];
            }
        }
    } else {
        // GENERAL PATH — arithmetic chain VERBATIM (rounds 1-10).
        for (int t0 = 0; t0 < TSTEPS; t0 += 64) {
#pragma unroll
            for (int i = 0; i < 32; i++) bufB[i] = rp[(size_t)(t0 + 32 + i) * HDIM];
            {
                float ss[32];
#pragma unroll
                for (int i = 0; i < 32; i++) {
                    m = (m + bufA[i]) + bias;
                    float thr = m / th - 1.0f;
                    ss[i] = (thr >= 0.0f) ? 1.0f : 0.0f;
                    if (thr > 0.0f) m -= th;
                }
#pragma unroll
                for (int i = 0; i < 32; i++) op[(size_t)(t0 + i) * HDIM] = ss[i];
            }
            if (t0 + 64 < TSTEPS) {
#pragma unroll
                for (int i = 0; i < 32; i++) bufA[i] = rp[(size_t)(t0 + 64 + i) * HDIM];
            }
            {
                float ss[32];
#pragma unroll
                for (int i = 0; i < 32; i++) {
                    m = (m + bufB[i]) + bias;
                    float thr = m / th - 1.0f;
                    ss[i] = (thr >= 0.0f) ? 1.0f : 0.0f;
                    if (thr > 0.0f) m -= th;
                }
#pragma unroll
                for (int i = 0; i < 32; i++) op[(size_t)(t0 + 32 + i) * HDIM] = ss[i];
            }
        }
    }
}

// ---------------------------------------------------------------------------
extern "C" void kernel_launch(void* const* d_in, const int* in_sizes, int n_in,
                              void* d_out, int out_size, void* d_ws, size_t ws_size,
                              hipStream_t stream) {
    const float* x    = (const float*)d_in[0];   // (64, 512, 256)
    const float* c1w  = (const float*)d_in[1];   // (512, 256, 3)
    const float* c1b  = (const float*)d_in[2];   // (512,)
    const float* c2w  = (const float*)d_in[3];   // (512, 512, 3)
    const float* c2b  = (const float*)d_in[4];   // (512,)
    const float* th1  = (const float*)d_in[5];   // scalar
    const float* th2  = (const float*)d_in[6];   // scalar
    float* out = (float*)d_out;                  // (64, 512, 512)

    // Workspace layout (floats):
    //   W1T  : 131072     (512 KB)  [k=i][n=h]
    //   W2T  : 513*512    (~1 MB)   [k=h][n=j] + zero pad row at k=512
    //   bufA : 16777216   (64 MB)   z1, later z2raw  [m][n]
    //   masks: 32768*8 u64 (2 MB)   spike bitmasks   [m][kword]
    float* W1T  = (float*)d_ws;
    float* W2T  = W1T + IDIM * HDIM;
    float* bufA = W2T + (HDIM + 1) * HDIM;
    unsigned long long* masks = (unsigned long long*)(bufA + (size_t)MROWS * HDIM);

    // K0: weight extraction (+ zero pad row)
    extract_weights<<<(HDIM * HDIM + 255) / 256, 256, 0, stream>>>(c1w, c2w, W1T, W2T);

    // K1: z1 = x @ W1T + b1   (M=32768, K=256, N=512) -> bufA
    {
        dim3 grid(MROWS / BM, HDIM / BN);
        gemm_f32<<<grid, 256, 0, stream>>>(x, W1T, c1b, bufA, IDIM, 1);
    }

    // K2: s1 scan -> spike bitmasks (no float s1 materialization)
    lif_scan1<<<MROWS / 64, 64, 0, stream>>>(bufA, masks, th1);

    // K3: z2raw[m][:] = sum_{k in spikes(m)} W2T[k][:]  (bit-exact sparse)
    spmm_spikes<<<MROWS, 64, 0, stream>>>(masks, W2T, bufA);

    // K4: s2 scan -> out
    lif_scan2<<<MROWS / 64, 64, 0, stream>>>(bufA, c2b, th2, out);
}